// Round 2
// baseline (682.060 us; speedup 1.0000x reference)
//
#include <hip/hip_runtime.h>

// SuperExpertMoE — round 2: routed sparsity (3x FLOP cut) + compacted per-expert GEMMs.
// gate -> route(compact) -> finalize -> casts -> up GEMM (per-expert, silu*combine, compacted)
//   -> down GEMM (per-expert, compacted, bf16 out) -> gather-sum (alpha/beta residual).

#define TOKS 4096
#define CD 2048
#define FD 1408
#define NE 9          // 8 routed + 1 shared
#define RROWS 8192    // exactly 2 slots per token
#define HROWS 12288   // 8192 routed + 4096 shared

typedef unsigned short u16;
typedef float f32x4 __attribute__((ext_vector_type(4)));
typedef __bf16 bf16x8 __attribute__((ext_vector_type(8)));

__device__ __forceinline__ u16 f2bf(float f) {
  unsigned u = __float_as_uint(f);
  u += 0x7fffu + ((u >> 16) & 1u);   // RNE
  return (u16)(u >> 16);
}

// ---------------- gating: one wave per token ----------------
__global__ __launch_bounds__(256) void gate_kernel(
    const float* __restrict__ x, const float* __restrict__ gw,
    float* __restrict__ combine, float* __restrict__ part, int* __restrict__ sel)
{
  const int lane = threadIdx.x & 63;
  const int wave = threadIdx.x >> 6;
  const int n = blockIdx.x * 4 + wave;
  const float* xr = x + (size_t)n * CD;
  float p[8] = {0,0,0,0,0,0,0,0};
#pragma unroll
  for (int it = 0; it < 8; ++it) {
    const int idx = it * 256 + lane * 4;
    const float4 xv = *(const float4*)(xr + idx);
#pragma unroll
    for (int e = 0; e < 8; ++e) {
      const float4 gv = *(const float4*)(gw + e * CD + idx);
      p[e] += xv.x * gv.x + xv.y * gv.y + xv.z * gv.z + xv.w * gv.w;
    }
  }
#pragma unroll
  for (int e = 0; e < 8; ++e) {
#pragma unroll
    for (int m = 32; m > 0; m >>= 1) p[e] += __shfl_xor(p[e], m, 64);
  }
  float mx = p[0];
#pragma unroll
  for (int e = 1; e < 8; ++e) mx = fmaxf(mx, p[e]);
  float s = 0.f, pr[8];
#pragma unroll
  for (int e = 0; e < 8; ++e) { pr[e] = __expf(p[e] - mx); s += pr[e]; }
  const float inv = 1.f / s;
#pragma unroll
  for (int e = 0; e < 8; ++e) pr[e] *= inv;
  const float lse = mx + __logf(s);
  int i1 = 0;
#pragma unroll
  for (int e = 1; e < 8; ++e) if (pr[e] > pr[i1]) i1 = e;   // strict > : lowest-index tie-break
  int i2 = (i1 == 0) ? 1 : 0;
#pragma unroll
  for (int e = 0; e < 8; ++e) if (e != i1 && pr[e] > pr[i2]) i2 = e;
  const float rs = 1.f / (pr[i1] + pr[i2]);

  __shared__ float pl[4][12];
  if (lane == 0) {
    float* cr = combine + (size_t)n * 16;
#pragma unroll
    for (int e = 0; e < 8; ++e) cr[e] = 0.f;
    cr[i1] = pr[i1] * rs;
    cr[i2] = pr[i2] * rs;
    cr[8] = 1.0f;                       // shared expert weight
    sel[n] = i1 | (i2 << 4);
#pragma unroll
    for (int e = 0; e < 8; ++e) pl[wave][e] = pr[e];
    pl[wave][8] = lse * lse;
  }
  __syncthreads();
  if (threadIdx.x < 9)
    part[(size_t)blockIdx.x * 16 + threadIdx.x] =
        pl[0][threadIdx.x] + pl[1][threadIdx.x] + pl[2][threadIdx.x] + pl[3][threadIdx.x];
}

// ---------------- routing compaction: single wave, deterministic ballot counting sort ----
// le[row] = token for routed rows [0,8192); pos[2n],pos[2n+1] = global compacted rows of token n.
// cntoff[e] = count, cntoff[16+e] = exclusive offset.
__global__ void route_kernel(const int* __restrict__ sel, int* __restrict__ le,
                             int* __restrict__ pos, int* __restrict__ cntoff)
{
  const int lane = threadIdx.x;
  const unsigned long long lt = (1ull << lane) - 1ull;
  int cnt[8] = {0,0,0,0,0,0,0,0};
  // pass 1: counts (ballot results uniform across lanes)
  for (int c = 0; c < TOKS / 64; ++c) {
    const int s = sel[c * 64 + lane];
    const int e1 = s & 15, e2 = (s >> 4) & 15;
#pragma unroll
    for (int e = 0; e < 8; ++e) {
      cnt[e] += __popcll(__ballot(e1 == e)) + __popcll(__ballot(e2 == e));
    }
  }
  int off[8]; off[0] = 0;
#pragma unroll
  for (int e = 1; e < 8; ++e) off[e] = off[e - 1] + cnt[e - 1];
  int base[8];
#pragma unroll
  for (int e = 0; e < 8; ++e) base[e] = off[e];
  // pass 2: assign rows in token order
  for (int c = 0; c < TOKS / 64; ++c) {
    const int n = c * 64 + lane;
    const int s = sel[n];
    const int e1 = s & 15, e2 = (s >> 4) & 15;
#pragma unroll
    for (int e = 0; e < 8; ++e) {
      const unsigned long long m1 = __ballot(e1 == e);
      const unsigned long long m2 = __ballot(e2 == e);
      if (e1 == e) { const int r = base[e] + __popcll(m1 & lt); le[r] = n; pos[2 * n] = r; }
      if (e2 == e) { const int r = base[e] + __popcll(m1) + __popcll(m2 & lt); le[r] = n; pos[2 * n + 1] = r; }
      base[e] += __popcll(m1) + __popcll(m2);
    }
  }
  if (lane < 8) { cntoff[lane] = cnt[lane]; cntoff[16 + lane] = off[lane]; }
  if (lane == 8) { cntoff[8] = TOKS; cntoff[24] = RROWS; }
}

// deterministic tree reduce of 1024 per-block partials -> loss scalar
__global__ void finalize_kernel(const float* __restrict__ part, float* __restrict__ loss_out)
{
  __shared__ float sm[256][10];
  float loc[9] = {0,0,0,0,0,0,0,0,0};
  for (int b = threadIdx.x; b < 1024; b += 256)
#pragma unroll
    for (int c = 0; c < 9; ++c) loc[c] += part[(size_t)b * 16 + c];
#pragma unroll
  for (int c = 0; c < 9; ++c) sm[threadIdx.x][c] = loc[c];
  __syncthreads();
  for (int off = 128; off > 0; off >>= 1) {
    if (threadIdx.x < off)
#pragma unroll
      for (int c = 0; c < 9; ++c) sm[threadIdx.x][c] += sm[threadIdx.x + off][c];
    __syncthreads();
  }
  if (threadIdx.x == 0) {
    float aux = 0.f;
#pragma unroll
    for (int e = 0; e < 8; ++e) { const float m = sm[0][e] * (1.f / TOKS); aux += m * m; }
    const float z = sm[0][8] * (1.f / TOKS);
    loss_out[0] = 0.01f * aux + 0.001f * z;
  }
}

// ---------------- casts ----------------
__global__ void cast4_kernel(const float4* __restrict__ in, u16* __restrict__ out, int n4)
{
  int i = blockIdx.x * blockDim.x + threadIdx.x;
  const int stride = gridDim.x * blockDim.x;
  for (; i < n4; i += stride) {
    const float4 v = in[i];
    ushort4 o;
    o.x = f2bf(v.x); o.y = f2bf(v.y); o.z = f2bf(v.z); o.w = f2bf(v.w);
    *(ushort4*)(out + (size_t)i * 4) = o;
  }
}

// ---------------- GEMM (m97-style): 128x128 tile, BK=64, per-expert blockIdx.z ----------------
// MODE 0 (up):   A = xb rows gathered via le (expert e token list), B = w1b[e], K=CD.
//                out Hcomp[(off[e]+row)*FD + col] = bf16(combine[tok][e] * silu(acc)), row<cnt.
// MODE 1 (down): A = Hcomp + off[e]*FD (contiguous), B = w2b[e], K=FD.
//                out Ycomp[(off[e]+row)*CD + col] = bf16(acc), row<cnt.
template<int MODE>
__global__ __launch_bounds__(256, 2) void gemm_bt(
    const u16* __restrict__ Abase, const u16* __restrict__ Bbase,
    u16* __restrict__ outBF,
    const float* __restrict__ combine,
    const int* __restrict__ le, const int* __restrict__ cntoff)
{
  constexpr int K = (MODE == 0) ? CD : FD;
  constexpr int OS = (MODE == 0) ? FD : CD;   // out row stride
  __shared__ __attribute__((aligned(16))) u16 smA[128 * 64];
  __shared__ __attribute__((aligned(16))) u16 smB[128 * 64];
  __shared__ int sh_tok[128];

  const int e = blockIdx.z;
  const int cnt = cntoff[e];
  const int m0 = blockIdx.x * 128;
  if (m0 >= cnt) return;
  const int off = cntoff[16 + e];
  const int n0 = blockIdx.y * 128;

  const int tid = threadIdx.x;
  const int lane = tid & 63;
  const int wave = tid >> 6;
  const int wr = wave >> 1, wc = wave & 1;

  const u16* A = (MODE == 0) ? Abase : (Abase + (size_t)off * FD);
  const u16* Bp = Bbase + (size_t)e * FD * CD;

  if (MODE == 0) {
    if (tid < 128) {
      const int i = m0 + tid;
      sh_tok[tid] = (e == 8) ? ((i < TOKS) ? i : 0) : ((i < cnt) ? le[off + i] : 0);
    }
    __syncthreads();
  }

  const int sub_r = lane >> 3;          // 0..7 : row within 8-row chunk
  const int sub_c = (lane & 7) << 3;    // 0,8,..,56 : col (elements)

  // per-thread A row indices for the 4 staging chunks
  int arow[4];
#pragma unroll
  for (int r = 0; r < 4; ++r) {
    const int lr = (wave * 4 + r) * 8 + sub_r;
    arow[r] = (MODE == 0) ? sh_tok[lr] : (m0 + lr);
  }

  f32x4 acc[4][4] = {};

  const int nkt = K >> 6;
  for (int kt = 0; kt < nkt; ++kt) {
    const int k0 = kt << 6;
#pragma unroll
    for (int r = 0; r < 4; ++r) {
      const int ch = (wave << 2) + r;
      const u16* ga = A + (size_t)arow[r] * K + k0 + sub_c;
      const u16* gb = Bp + (size_t)(n0 + ch * 8 + sub_r) * K + k0 + sub_c;
      __builtin_amdgcn_global_load_lds((const __attribute__((address_space(1))) void*)ga,
                                       (__attribute__((address_space(3))) void*)(smA + ch * 512),
                                       16, 0, 0);
      __builtin_amdgcn_global_load_lds((const __attribute__((address_space(1))) void*)gb,
                                       (__attribute__((address_space(3))) void*)(smB + ch * 512),
                                       16, 0, 0);
    }
    asm volatile("s_waitcnt vmcnt(0)" ::: "memory");
    __syncthreads();
#pragma unroll
    for (int kk = 0; kk < 2; ++kk) {
      const int ko = (kk << 5) + ((lane >> 4) << 3);
      bf16x8 af[4], bfv[4];
#pragma unroll
      for (int i = 0; i < 4; ++i)
        af[i] = *(const bf16x8*)(smA + ((wr * 64 + i * 16 + (lane & 15)) << 6) + ko);
#pragma unroll
      for (int j = 0; j < 4; ++j)
        bfv[j] = *(const bf16x8*)(smB + ((wc * 64 + j * 16 + (lane & 15)) << 6) + ko);
#pragma unroll
      for (int i = 0; i < 4; ++i)
#pragma unroll
        for (int j = 0; j < 4; ++j)
          acc[i][j] = __builtin_amdgcn_mfma_f32_16x16x32_bf16(af[i], bfv[j], acc[i][j], 0, 0, 0);
    }
    __syncthreads();
  }

  // epilogue — C/D layout: col = lane&15, row = (lane>>4)*4 + q
#pragma unroll
  for (int i = 0; i < 4; ++i) {
    const int rloc0 = wr * 64 + i * 16 + ((lane >> 4) << 2);
#pragma unroll
    for (int j = 0; j < 4; ++j) {
      const int col = n0 + wc * 64 + j * 16 + (lane & 15);
#pragma unroll
      for (int q = 0; q < 4; ++q) {
        const int rloc = rloc0 + q;
        if (m0 + rloc >= cnt) continue;
        const float v = acc[i][j][q];
        float h;
        if (MODE == 0) {
          const int tok = sh_tok[rloc];
          const float sc = combine[(size_t)tok * 16 + e];
          h = sc * v * (1.f / (1.f + __expf(-v)));
        } else {
          h = v;
        }
        outBF[(size_t)(off + m0 + rloc) * OS + col] = f2bf(h);
      }
    }
  }
}

// ---------------- gather-sum: out[n] = alpha*(Yc[p1]+Yc[p2]+Yc[8192+n]) + beta*x[n] --------
__global__ __launch_bounds__(256) void gather_kernel(
    const u16* __restrict__ Yc, const int* __restrict__ pos,
    const float* __restrict__ x, const float* __restrict__ alpha,
    const float* __restrict__ beta, float* __restrict__ out)
{
  const int n = blockIdx.x;
  const int c0 = threadIdx.x * 8;
  const int p1 = pos[2 * n], p2 = pos[2 * n + 1];
  const bf16x8 a = *(const bf16x8*)(Yc + (size_t)p1 * CD + c0);
  const bf16x8 b = *(const bf16x8*)(Yc + (size_t)p2 * CD + c0);
  const bf16x8 s = *(const bf16x8*)(Yc + ((size_t)RROWS + n) * CD + c0);
  const float* xr = x + (size_t)n * CD + c0;
  float* orow = out + (size_t)n * CD + c0;
#pragma unroll
  for (int j = 0; j < 8; ++j) {
    const float v = (float)a[j] + (float)b[j] + (float)s[j];
    orow[j] = alpha[c0 + j] * v + beta[c0 + j] * xr[j];
  }
}

extern "C" void kernel_launch(void* const* d_in, const int* in_sizes, int n_in,
                              void* d_out, int out_size, void* d_ws, size_t ws_size,
                              hipStream_t stream)
{
  (void)in_sizes; (void)n_in; (void)out_size; (void)ws_size;
  const float* x     = (const float*)d_in[0];
  const float* gw    = (const float*)d_in[1];
  const float* w1    = (const float*)d_in[2];
  const float* w2    = (const float*)d_in[3];
  const float* sw1   = (const float*)d_in[4];
  const float* sw2   = (const float*)d_in[5];
  const float* alpha = (const float*)d_in[6];
  const float* beta  = (const float*)d_in[7];
  float* out = (float*)d_out;

  // workspace layout (~206 MB)
  char* ws = (char*)d_ws;
  float* combine = (float*)(ws + 0);            // 256 KB
  float* part    = (float*)(ws + 262144);       // 64 KB
  int*   sel     = (int*)(ws + 327680);         // 16 KB
  int*   le      = (int*)(ws + 344064);         // 32 KB
  int*   pos     = (int*)(ws + 376832);         // 32 KB
  int*   cntoff  = (int*)(ws + 409600);         // 256 B
  u16*   xb      = (u16*)(ws + 409856);         // 16 MB
  u16*   w1b     = (u16*)(ws + 17187072);       // 51.9 MB (w1 x8 then sw1)
  u16*   w2b     = (u16*)(ws + 69091584);       // 51.9 MB (w2 x8 then sw2)
  u16*   Hcomp   = (u16*)(ws + 120996096);      // 12288*1408*2 = 34.6 MB
  u16*   Ycomp   = (u16*)(ws + 155599104);      // 12288*2048*2 = 50.3 MB

  gate_kernel<<<1024, 256, 0, stream>>>(x, gw, combine, part, sel);
  route_kernel<<<1, 64, 0, stream>>>(sel, le, pos, cntoff);
  finalize_kernel<<<1, 256, 0, stream>>>(part, out + (size_t)TOKS * CD);
  cast4_kernel<<<1024, 256, 0, stream>>>((const float4*)x, xb, TOKS * CD / 4);
  cast4_kernel<<<2048, 256, 0, stream>>>((const float4*)w1, w1b, 8 * FD * CD / 4);
  cast4_kernel<<<1024, 256, 0, stream>>>((const float4*)sw1, w1b + (size_t)8 * FD * CD, FD * CD / 4);
  cast4_kernel<<<2048, 256, 0, stream>>>((const float4*)w2, w2b, 8 * CD * FD / 4);
  cast4_kernel<<<1024, 256, 0, stream>>>((const float4*)sw2, w2b + (size_t)8 * CD * FD, CD * FD / 4);
  gemm_bt<0><<<dim3(32, 11, 9), 256, 0, stream>>>(xb, w1b, Hcomp, combine, le, cntoff);
  gemm_bt<1><<<dim3(32, 16, 9), 256, 0, stream>>>(Hcomp, w2b, Ycomp, nullptr, nullptr, cntoff);
  gather_kernel<<<TOKS, 256, 0, stream>>>(Ycomp, pos, x, alpha, beta, out);
}

// Round 3
// 409.271 us; speedup vs baseline: 1.6665x; 1.6665x over previous
//
#include <hip/hip_runtime.h>

// SuperExpertMoE — round 3: flat tile map (dense working grid) + XCD-chunk swizzle + fused casts.
// gate -> route(compact + tile map) -> finalize -> fused cast -> up GEMM -> down GEMM -> gather.

#define TOKS 4096
#define CD 2048
#define FD 1408
#define RROWS 8192    // exactly 2 routed slots per token
#define NTMAX 104     // max m-tiles: sum ceil(cnt_e/128) (<=72) + 32 shared

typedef unsigned short u16;
typedef float f32x4 __attribute__((ext_vector_type(4)));
typedef __bf16 bf16x8 __attribute__((ext_vector_type(8)));

__device__ __forceinline__ u16 f2bf(float f) {
  unsigned u = __float_as_uint(f);
  u += 0x7fffu + ((u >> 16) & 1u);   // RNE
  return (u16)(u >> 16);
}

// ---------------- gating: one wave per token ----------------
__global__ __launch_bounds__(256) void gate_kernel(
    const float* __restrict__ x, const float* __restrict__ gw,
    float* __restrict__ combine, float* __restrict__ part, int* __restrict__ sel)
{
  const int lane = threadIdx.x & 63;
  const int wave = threadIdx.x >> 6;
  const int n = blockIdx.x * 4 + wave;
  const float* xr = x + (size_t)n * CD;
  float p[8] = {0,0,0,0,0,0,0,0};
#pragma unroll
  for (int it = 0; it < 8; ++it) {
    const int idx = it * 256 + lane * 4;
    const float4 xv = *(const float4*)(xr + idx);
#pragma unroll
    for (int e = 0; e < 8; ++e) {
      const float4 gv = *(const float4*)(gw + e * CD + idx);
      p[e] += xv.x * gv.x + xv.y * gv.y + xv.z * gv.z + xv.w * gv.w;
    }
  }
#pragma unroll
  for (int e = 0; e < 8; ++e) {
#pragma unroll
    for (int m = 32; m > 0; m >>= 1) p[e] += __shfl_xor(p[e], m, 64);
  }
  float mx = p[0];
#pragma unroll
  for (int e = 1; e < 8; ++e) mx = fmaxf(mx, p[e]);
  float s = 0.f, pr[8];
#pragma unroll
  for (int e = 0; e < 8; ++e) { pr[e] = __expf(p[e] - mx); s += pr[e]; }
  const float inv = 1.f / s;
#pragma unroll
  for (int e = 0; e < 8; ++e) pr[e] *= inv;
  const float lse = mx + __logf(s);
  int i1 = 0;
#pragma unroll
  for (int e = 1; e < 8; ++e) if (pr[e] > pr[i1]) i1 = e;   // strict > : lowest-index tie-break
  int i2 = (i1 == 0) ? 1 : 0;
#pragma unroll
  for (int e = 0; e < 8; ++e) if (e != i1 && pr[e] > pr[i2]) i2 = e;
  const float rs = 1.f / (pr[i1] + pr[i2]);

  __shared__ float pl[4][12];
  if (lane == 0) {
    float* cr = combine + (size_t)n * 16;
#pragma unroll
    for (int e = 0; e < 8; ++e) cr[e] = 0.f;
    cr[i1] = pr[i1] * rs;
    cr[i2] = pr[i2] * rs;
    cr[8] = 1.0f;
    sel[n] = i1 | (i2 << 4);
#pragma unroll
    for (int e = 0; e < 8; ++e) pl[wave][e] = pr[e];
    pl[wave][8] = lse * lse;
  }
  __syncthreads();
  if (threadIdx.x < 9)
    part[(size_t)blockIdx.x * 16 + threadIdx.x] =
        pl[0][threadIdx.x] + pl[1][threadIdx.x] + pl[2][threadIdx.x] + pl[3][threadIdx.x];
}

// ---------------- routing compaction (single wave, deterministic) + flat tile map --------
__global__ void route_kernel(const int* __restrict__ sel, int* __restrict__ le,
                             int* __restrict__ pos, int* __restrict__ cntoff,
                             int* __restrict__ tileMap)
{
  const int lane = threadIdx.x;
  const unsigned long long lt = (1ull << lane) - 1ull;
  int cnt[8] = {0,0,0,0,0,0,0,0};
  for (int c = 0; c < TOKS / 64; ++c) {
    const int s = sel[c * 64 + lane];
    const int e1 = s & 15, e2 = (s >> 4) & 15;
#pragma unroll
    for (int e = 0; e < 8; ++e)
      cnt[e] += __popcll(__ballot(e1 == e)) + __popcll(__ballot(e2 == e));
  }
  int off[8]; off[0] = 0;
#pragma unroll
  for (int e = 1; e < 8; ++e) off[e] = off[e - 1] + cnt[e - 1];
  int base[8];
#pragma unroll
  for (int e = 0; e < 8; ++e) base[e] = off[e];
  for (int c = 0; c < TOKS / 64; ++c) {
    const int n = c * 64 + lane;
    const int s = sel[n];
    const int e1 = s & 15, e2 = (s >> 4) & 15;
#pragma unroll
    for (int e = 0; e < 8; ++e) {
      const unsigned long long m1 = __ballot(e1 == e);
      const unsigned long long m2 = __ballot(e2 == e);
      if (e1 == e) { const int r = base[e] + __popcll(m1 & lt); le[r] = n; pos[2 * n] = r; }
      if (e2 == e) { const int r = base[e] + __popcll(m1) + __popcll(m2 & lt); le[r] = n; pos[2 * n + 1] = r; }
      base[e] += __popcll(m1) + __popcll(m2);
    }
  }
  if (lane < 8) { cntoff[lane] = cnt[lane]; cntoff[16 + lane] = off[lane]; }
  if (lane == 8) { cntoff[8] = TOKS; cntoff[24] = RROWS; }
  if (lane == 0) {
    int t = 0;
    for (int e = 0; e < 8; ++e)
      for (int m = 0; m < cnt[e]; m += 128) tileMap[t++] = e | (m << 4);
    for (int m = 0; m < TOKS; m += 128) tileMap[t++] = 8 | (m << 4);
    cntoff[25] = t;   // NT <= 104
  }
}

// deterministic tree reduce -> loss scalar
__global__ void finalize_kernel(const float* __restrict__ part, float* __restrict__ loss_out)
{
  __shared__ float sm[256][10];
  float loc[9] = {0,0,0,0,0,0,0,0,0};
  for (int b = threadIdx.x; b < 1024; b += 256)
#pragma unroll
    for (int c = 0; c < 9; ++c) loc[c] += part[(size_t)b * 16 + c];
#pragma unroll
  for (int c = 0; c < 9; ++c) sm[threadIdx.x][c] = loc[c];
  __syncthreads();
  for (int off = 128; off > 0; off >>= 1) {
    if (threadIdx.x < off)
#pragma unroll
      for (int c = 0; c < 9; ++c) sm[threadIdx.x][c] += sm[threadIdx.x + off][c];
    __syncthreads();
  }
  if (threadIdx.x == 0) {
    float aux = 0.f;
#pragma unroll
    for (int e = 0; e < 8; ++e) { const float m = sm[0][e] * (1.f / TOKS); aux += m * m; }
    const float z = sm[0][8] * (1.f / TOKS);
    loss_out[0] = 0.01f * aux + 0.001f * z;
  }
}

// ---------------- fused cast: x, w1, sw1, w2, sw2 -> bf16 in one dispatch ----------------
#define X4   2097152   // TOKS*CD/4
#define W14  5767168   // 8*FD*CD/4
#define SW14 720896    // FD*CD/4
__global__ void cast_all_kernel(const float4* __restrict__ x,  const float4* __restrict__ w1,
                                const float4* __restrict__ sw1, const float4* __restrict__ w2,
                                const float4* __restrict__ sw2,
                                u16* __restrict__ xb, u16* __restrict__ w1b, u16* __restrict__ w2b)
{
  const int total = X4 + 2 * (W14 + SW14);
  int i = blockIdx.x * blockDim.x + threadIdx.x;
  const int stride = gridDim.x * blockDim.x;
  for (; i < total; i += stride) {
    int j = i;
    const float4* src; u16* dst;
    if (j < X4)                    { src = x;   dst = xb; }
    else if ((j -= X4) < W14)      { src = w1;  dst = w1b; }
    else if ((j -= W14) < SW14)    { src = sw1; dst = w1b + (size_t)8 * FD * CD; }
    else if ((j -= SW14) < W14)    { src = w2;  dst = w2b; }
    else                           { j -= W14; src = sw2; dst = w2b + (size_t)8 * CD * FD; }
    const float4 v = src[j];
    ushort4 o;
    o.x = f2bf(v.x); o.y = f2bf(v.y); o.z = f2bf(v.z); o.w = f2bf(v.w);
    *(ushort4*)(dst + (size_t)j * 4) = o;
  }
}

// ---------------- GEMM (m97-style), flat tile map, XCD-chunk swizzled ----------------
// MODE 0 (up):   A = xb gathered via le; B = w1b[e]; out Hcomp (silu*combine), K=CD, NY=11.
// MODE 1 (down): A = Hcomp + off[e]*FD; B = w2b[e]; out Ycomp (bf16), K=FD, NY=16.
template<int MODE>
__global__ __launch_bounds__(256, 2) void gemm_bt(
    const u16* __restrict__ Abase, const u16* __restrict__ Bbase,
    u16* __restrict__ outBF, const float* __restrict__ combine,
    const int* __restrict__ le, const int* __restrict__ cntoff,
    const int* __restrict__ tileMap)
{
  constexpr int K  = (MODE == 0) ? CD : FD;
  constexpr int OS = (MODE == 0) ? FD : CD;
  constexpr int NY = (MODE == 0) ? 11 : 16;
  constexpr int Q  = NTMAX * NY / 8;     // 1144/8=143, 1664/8=208 (exact)

  __shared__ __attribute__((aligned(16))) u16 smA[128 * 64];
  __shared__ __attribute__((aligned(16))) u16 smB[128 * 64];
  __shared__ int sh_tok[128];

  // bijective XCD-chunk swizzle: contiguous logical ids (same expert) -> same XCD
  const int orig = blockIdx.x + gridDim.x * blockIdx.y;
  const int wgid = (orig & 7) * Q + (orig >> 3);
  const int t = wgid / NY;
  const int y = wgid - t * NY;
  const int NT = cntoff[25];
  if (t >= NT) return;
  const int packed = tileMap[t];
  const int e = packed & 15;
  const int m0 = packed >> 4;
  const int cnt = cntoff[e];
  const int off = cntoff[16 + e];
  const int n0 = y * 128;

  const int tid = threadIdx.x;
  const int lane = tid & 63;
  const int wave = tid >> 6;
  const int wr = wave >> 1, wc = wave & 1;

  const u16* A = (MODE == 0) ? Abase : (Abase + (size_t)off * FD);
  const u16* Bp = Bbase + (size_t)e * FD * CD;

  if (MODE == 0) {
    if (tid < 128) {
      const int i = m0 + tid;
      sh_tok[tid] = (e == 8) ? i : ((i < cnt) ? le[off + i] : 0);
    }
    __syncthreads();
  }

  const int sub_r = lane >> 3;
  const int sub_c = (lane & 7) << 3;

  int arow[4];
#pragma unroll
  for (int r = 0; r < 4; ++r) {
    const int lr = (wave * 4 + r) * 8 + sub_r;
    arow[r] = (MODE == 0) ? sh_tok[lr] : (m0 + lr);
  }

  f32x4 acc[4][4] = {};

  const int nkt = K >> 6;
  for (int kt = 0; kt < nkt; ++kt) {
    const int k0 = kt << 6;
#pragma unroll
    for (int r = 0; r < 4; ++r) {
      const int ch = (wave << 2) + r;
      const u16* ga = A + (size_t)arow[r] * K + k0 + sub_c;
      const u16* gb = Bp + (size_t)(n0 + ch * 8 + sub_r) * K + k0 + sub_c;
      __builtin_amdgcn_global_load_lds((const __attribute__((address_space(1))) void*)ga,
                                       (__attribute__((address_space(3))) void*)(smA + ch * 512),
                                       16, 0, 0);
      __builtin_amdgcn_global_load_lds((const __attribute__((address_space(1))) void*)gb,
                                       (__attribute__((address_space(3))) void*)(smB + ch * 512),
                                       16, 0, 0);
    }
    asm volatile("s_waitcnt vmcnt(0)" ::: "memory");
    __syncthreads();
#pragma unroll
    for (int kk = 0; kk < 2; ++kk) {
      const int ko = (kk << 5) + ((lane >> 4) << 3);
      bf16x8 af[4], bfv[4];
#pragma unroll
      for (int i = 0; i < 4; ++i)
        af[i] = *(const bf16x8*)(smA + ((wr * 64 + i * 16 + (lane & 15)) << 6) + ko);
#pragma unroll
      for (int j = 0; j < 4; ++j)
        bfv[j] = *(const bf16x8*)(smB + ((wc * 64 + j * 16 + (lane & 15)) << 6) + ko);
#pragma unroll
      for (int i = 0; i < 4; ++i)
#pragma unroll
        for (int j = 0; j < 4; ++j)
          acc[i][j] = __builtin_amdgcn_mfma_f32_16x16x32_bf16(af[i], bfv[j], acc[i][j], 0, 0, 0);
    }
    __syncthreads();
  }

  // epilogue — C/D layout: col = lane&15, row = (lane>>4)*4 + q
#pragma unroll
  for (int i = 0; i < 4; ++i) {
    const int rloc0 = wr * 64 + i * 16 + ((lane >> 4) << 2);
#pragma unroll
    for (int j = 0; j < 4; ++j) {
      const int col = n0 + wc * 64 + j * 16 + (lane & 15);
#pragma unroll
      for (int q = 0; q < 4; ++q) {
        const int rloc = rloc0 + q;
        if (m0 + rloc >= cnt) continue;
        const float v = acc[i][j][q];
        float h;
        if (MODE == 0) {
          const int tok = sh_tok[rloc];
          const float sc = combine[(size_t)tok * 16 + e];
          h = sc * v * (1.f / (1.f + __expf(-v)));
        } else {
          h = v;
        }
        outBF[(size_t)(off + m0 + rloc) * OS + col] = f2bf(h);
      }
    }
  }
}

// ---------------- gather-sum: out[n] = alpha*(Yc[p1]+Yc[p2]+Yc[8192+n]) + beta*x[n] --------
__global__ __launch_bounds__(256) void gather_kernel(
    const u16* __restrict__ Yc, const int* __restrict__ pos,
    const float* __restrict__ x, const float* __restrict__ alpha,
    const float* __restrict__ beta, float* __restrict__ out)
{
  const int n = blockIdx.x;
  const int c0 = threadIdx.x * 8;
  const int p1 = pos[2 * n], p2 = pos[2 * n + 1];
  const bf16x8 a = *(const bf16x8*)(Yc + (size_t)p1 * CD + c0);
  const bf16x8 b = *(const bf16x8*)(Yc + (size_t)p2 * CD + c0);
  const bf16x8 s = *(const bf16x8*)(Yc + ((size_t)RROWS + n) * CD + c0);
  const float* xr = x + (size_t)n * CD + c0;
  float* orow = out + (size_t)n * CD + c0;
#pragma unroll
  for (int j = 0; j < 8; ++j) {
    const float v = (float)a[j] + (float)b[j] + (float)s[j];
    orow[j] = alpha[c0 + j] * v + beta[c0 + j] * xr[j];
  }
}

extern "C" void kernel_launch(void* const* d_in, const int* in_sizes, int n_in,
                              void* d_out, int out_size, void* d_ws, size_t ws_size,
                              hipStream_t stream)
{
  (void)in_sizes; (void)n_in; (void)out_size; (void)ws_size;
  const float* x     = (const float*)d_in[0];
  const float* gw    = (const float*)d_in[1];
  const float* w1    = (const float*)d_in[2];
  const float* w2    = (const float*)d_in[3];
  const float* sw1   = (const float*)d_in[4];
  const float* sw2   = (const float*)d_in[5];
  const float* alpha = (const float*)d_in[6];
  const float* beta  = (const float*)d_in[7];
  float* out = (float*)d_out;

  char* ws = (char*)d_ws;
  float* combine = (float*)(ws + 0);            // 256 KB
  float* part    = (float*)(ws + 262144);       // 64 KB
  int*   sel     = (int*)(ws + 327680);         // 16 KB
  int*   le      = (int*)(ws + 344064);         // 32 KB
  int*   pos     = (int*)(ws + 376832);         // 32 KB
  int*   cntoff  = (int*)(ws + 409600);         // 256 B
  int*   tileMap = (int*)(ws + 409856);         // 512 B
  u16*   xb      = (u16*)(ws + 410368);         // 16 MB
  u16*   w1b     = (u16*)(ws + 17187584);       // 51.9 MB (w1 x8, then sw1)
  u16*   w2b     = (u16*)(ws + 69092096);       // 51.9 MB (w2 x8, then sw2)
  u16*   Hcomp   = (u16*)(ws + 120996608);      // 12288*1408*2 = 34.6 MB
  u16*   Ycomp   = (u16*)(ws + 155599616);      // 12288*2048*2 = 50.3 MB

  gate_kernel<<<1024, 256, 0, stream>>>(x, gw, combine, part, sel);
  route_kernel<<<1, 64, 0, stream>>>(sel, le, pos, cntoff, tileMap);
  finalize_kernel<<<1, 256, 0, stream>>>(part, out + (size_t)TOKS * CD);
  cast_all_kernel<<<4096, 256, 0, stream>>>((const float4*)x, (const float4*)w1,
                                            (const float4*)sw1, (const float4*)w2,
                                            (const float4*)sw2, xb, w1b, w2b);
  gemm_bt<0><<<dim3(NTMAX, 11), 256, 0, stream>>>(xb, w1b, Hcomp, combine, le, cntoff, tileMap);
  gemm_bt<1><<<dim3(NTMAX, 16), 256, 0, stream>>>(Hcomp, w2b, Ycomp, nullptr, nullptr, cntoff, tileMap);
  gather_kernel<<<TOKS, 256, 0, stream>>>(Ycomp, pos, x, alpha, beta, out);
}